// Round 6
// baseline (363.441 us; speedup 1.0000x reference)
//
#include <hip/hip_runtime.h>
#include <stdint.h>

// Problem constants (fixed by reference)
#define TP_      8
#define M_DIM    4096
#define K_DIM    8192
#define N_DIM    1024      // N_LOCAL
#define KL_      1024      // K_LOCAL
#define BM       128
#define BN       256
#define SPLITK   2
#define KSLICE   (K_DIM / SPLITK)   // 4096
#define NT       (KSLICE / 64)      // 64 K-steps of BK=64
#define MN4      (M_DIM * N_DIM / 4)
#define KCHUNKS  (K_DIM / 32)       // 256 k32-chunks per 16-col group (Bfrag)

typedef _Float16 f16;
typedef f16 f16x8 __attribute__((ext_vector_type(8)));
typedef f16 f16x4 __attribute__((ext_vector_type(4)));
typedef float f32x4 __attribute__((ext_vector_type(4)));

// 8x fp32 -> fp16 (v_cvt_f16_f32, RN)
__device__ __forceinline__ f16x8 cvt8(float4 a, float4 b) {
    f16x8 r;
    r[0] = (f16)a.x; r[1] = (f16)a.y; r[2] = (f16)a.z; r[3] = (f16)a.w;
    r[4] = (f16)b.x; r[5] = (f16)b.y; r[6] = (f16)b.z; r[7] = (f16)b.w;
    return r;
}

// async global->LDS, 16B/lane; dest = wave-uniform base + lane*16 (m104/m108);
// global source IS per-lane -> swizzled LDS layout via pre-swizzled source (m173).
__device__ __forceinline__ void lds_load16(const void* g, void* l) {
    __builtin_amdgcn_global_load_lds(
        (const __attribute__((address_space(1))) void*)g,
        (__attribute__((address_space(3))) void*)l, 16, 0, 0);
}

// ---------- kernel 1: convert + repack W -> fragment-major fp16 (r2-verified) ----------
// Bfrag chunk c = colgroup*KCHUNKS + k32; 512 halfs; slot lane*8 =
// W[k32*32 + (lane>>4)*8 ..+8][group*16 + (lane&15)].
__global__ __launch_bounds__(256) void conv_w_kernel(
        const float* __restrict__ W, f16* __restrict__ Bfrag) {
    __shared__ float tile[64][68];                 // [k][n], pad 68
    const int t  = threadIdx.x;
    const int n0 = blockIdx.x * 64;
    const int k0 = blockIdx.y * 64;
    #pragma unroll
    for (int l = 0; l < 4; l++) {
        int kr = l * 16 + (t >> 4);
        float4 v = *(const float4*)&W[(size_t)(k0 + kr) * N_DIM + n0 + (t & 15) * 4];
        *(float4*)&tile[kr][(t & 15) * 4] = v;
    }
    __syncthreads();
    const int jtl   = t >> 6;
    const int kt32l = (t >> 5) & 1;
    const int u     = t & 31;
    const int rr    = u & 15;
    const int qp    = u >> 4;
    f16x8 h0, h1;
    #pragma unroll
    for (int kk = 0; kk < 8; kk++)
        h0[kk] = (f16)tile[kt32l * 32 + qp * 16 + kk][jtl * 16 + rr];
    #pragma unroll
    for (int kk = 0; kk < 8; kk++)
        h1[kk] = (f16)tile[kt32l * 32 + qp * 16 + 8 + kk][jtl * 16 + rr];
    size_t chunk = (size_t)(n0 / 16 + jtl) * KCHUNKS + (k0 / 32 + kt32l);
    f16* dst = Bfrag + chunk * 512;
    *(f16x8*)(dst + ((2 * qp)     * 16 + rr) * 8) = h0;
    *(f16x8*)(dst + ((2 * qp + 1) * 16 + rr) * 8) = h1;
}

// ---------- kernel 2: fused A-direct deep-pipelined GEMM ----------
// r5 lesson: conv-A's 2 TB/s wall is traffic-shape-invariant -> delete the
// Afrag round trip entirely. A is staged fp32 DIRECTLY from act via
// global_load_lds with XOR-swizzled per-lane SOURCE addresses (m173):
//   LDS A subtile [16 rows][32 k] fp32, byte(row,col) = row*128 + ((col*4) ^ ((row&7)<<4))
//   staging inst j: lane l -> row j*8+(l>>3), col 4*((l&7)^(l>>3)): 8 FULL
//   128B lines per inst (coalesced); frag read: 2x ds_read_b128 at
//   rr*128 + (((2q)^(rr&7))<<4) and ^16 -> 8 lanes/bank-quad = conflict-free.
// BM=128 halves per-wave m-frags, exactly canceling fp32's 2x LDS-read bytes
// (LDS/CU/k32 ~1152cy < MFMA 1241cy). SPLITK=2, 256 blocks, 8 waves (2Mx4N).
// Schedule: r2-verified rhythm, 2 phases/K-step (k2), 16-MFMA clusters,
// counted vmcnt(4) (4 gl_lds per slot), drain only at tail.
__global__ __launch_bounds__(512, 2) void gemm_fused_kernel(
        const float* __restrict__ act,        // (TP, M, KL) fp32
        const f16* __restrict__ Bfrag,
        f16* __restrict__ part) {             // (SPLITK, M, N) fp16
    __shared__ __align__(16) char smraw[131072];  // A 64KB | B 64KB
    char* const smA = smraw;
    char* const smB = smraw + 65536;

    const int tid  = threadIdx.x;
    const int w    = tid >> 6;                // wave 0..7
    const int lane = tid & 63;
    const int q    = lane >> 4;
    const int rr   = lane & 15;
    const int wr   = w >> 2;                  // 0..1 (M)
    const int wc   = w & 3;                   // 0..3 (N)

    // XCD decode: xcd owns one z and 8 mb panels; 4 nb-siblings adjacent
    // in slot order -> A panel L2-reused x4. A read once from HBM total.
    const int id   = blockIdx.x;              // 0..255
    const int xcd  = id & 7;
    const int slot = id >> 3;                 // 0..31
    const int z    = xcd & 1;                 // 0..1
    const int mgrp = xcd >> 1;                // 0..3
    const int mb   = (slot >> 2) * 4 + mgrp;  // 0..31
    const int nb   = slot & 3;                // 0..3
    const int row0 = mb * BM;
    const int col0 = nb * BN;
    const int kb32 = z * (KSLICE / 32);       // first k32 of this z-slice
    const int ng0  = col0 >> 4;

    // per-lane constants
    const int aColX  = (((lane & 7) ^ (lane >> 3)) << 2);       // float offset in row
    const int aRowIn = lane >> 3;                                // row within 8-row inst
    const int aOff0  = rr * 128 + ((((2 * q)) ^ (rr & 7)) << 4); // frag read lo
    // frag read hi = aOff0 ^ 16

    f32x4 acc[4][4];
    #pragma unroll
    for (int m = 0; m < 4; m++)
        #pragma unroll
        for (int n = 0; n < 4; n++)
            acc[m][n] = (f32x4){0.f, 0.f, 0.f, 0.f};

    f16x8 af[4];
    f16x8 bf[4];

// A: stage subtile mg=w of k32 (kb32+2T+K2): 2 insts, each 8 full 128B lines.
#define STAGE_A(B_, T_, K2_) do { \
    const int kt32_ = kb32 + 2 * (T_) + (K2_); \
    const int r_  = kt32_ >> 5; \
    const int kl_ = (kt32_ & 31) * 32; \
    _Pragma("unroll") \
    for (int j_ = 0; j_ < 2; j_++) { \
        const float* g_ = act + ((size_t)r_ * M_DIM + row0 + w * 16 + j_ * 8 + aRowIn) * KL_ \
                          + kl_ + aColX; \
        lds_load16(g_, smA + (((B_) * 2 + (K2_)) * 8 + w) * 2048 + j_ * 1024 + lane * 16); \
    } \
} while (0)

// B: stage chunks ng=2w,2w+1 of k32: 2 insts, contiguous 1KB each.
#define STAGE_B(B_, T_, K2_) do { \
    const int kt32_ = kb32 + 2 * (T_) + (K2_); \
    _Pragma("unroll") \
    for (int j_ = 0; j_ < 2; j_++) { \
        const int ng_ = 2 * w + j_; \
        const f16* g_ = Bfrag + ((size_t)(ng0 + ng_) * KCHUNKS + kt32_) * 512 + lane * 8; \
        lds_load16(g_, smB + (((B_) * 2 + (K2_)) * 16 + ng_) * 1024 + lane * 16); \
    } \
} while (0)

// A frags: mg = wr*4+mi; swizzled pair of b128 -> cvt to f16x8.
#define READ_A(B_, K2_) do { \
    _Pragma("unroll") \
    for (int mi_ = 0; mi_ < 4; mi_++) { \
        const char* b_ = smA + (((B_) * 2 + (K2_)) * 8 + wr * 4 + mi_) * 2048 + aOff0; \
        float4 x_ = *(const float4*)(b_); \
        float4 y_ = *(const float4*)(b_ + ((aOff0 ^ 16) - aOff0)); \
        af[mi_] = cvt8(x_, y_); \
    } \
} while (0)

#define READ_B(B_, K2_) do { \
    _Pragma("unroll") \
    for (int ni_ = 0; ni_ < 4; ni_++) \
        bf[ni_] = *(const f16x8*)(smB + (((B_) * 2 + (K2_)) * 16 + wc * 4 + ni_) * 1024 + lane * 16); \
} while (0)

#define MFMA16() do { \
    __builtin_amdgcn_s_setprio(1); \
    _Pragma("unroll") \
    for (int mi_ = 0; mi_ < 4; mi_++) \
        _Pragma("unroll") \
        for (int ni_ = 0; ni_ < 4; ni_++) \
            acc[mi_][ni_] = __builtin_amdgcn_mfma_f32_16x16x32_f16( \
                af[mi_], bf[ni_], acc[mi_][ni_], 0, 0, 0); \
    __builtin_amdgcn_s_setprio(0); \
} while (0)

#define BAR() do { \
    asm volatile("" ::: "memory"); \
    __builtin_amdgcn_s_barrier(); \
    asm volatile("" ::: "memory"); \
} while (0)
#define SBAR0() __builtin_amdgcn_sched_barrier(0)
#define VM4() asm volatile("s_waitcnt vmcnt(4)" ::: "memory")
#define VM0() asm volatile("s_waitcnt vmcnt(0)" ::: "memory")

// Ledger (per wave, 4 insts/slot): entering tile t outstanding = slot1(t)=4.
// ph0: read slot0(t) [landed]; issue slot0(t+1) -> 8; MFMA; VMMID=vm4 retires
//      slot1(t) -> 4. ph1: read slot1(t); issue slot1(t+1) -> 8; MFMA;
//      VMEND=vm4 retires slot0(t+1) -> 4. Invariant restored.
#define TILE(P_, T_, STG_, VMMID_, VMEND_) do { \
    READ_A(P_, 0); READ_B(P_, 0); \
    if (STG_) { STAGE_A((P_) ^ 1, (T_) + 1, 0); STAGE_B((P_) ^ 1, (T_) + 1, 0); } \
    BAR(); SBAR0(); MFMA16(); VMMID_; BAR(); \
    READ_A(P_, 1); READ_B(P_, 1); \
    if (STG_) { STAGE_A((P_) ^ 1, (T_) + 1, 1); STAGE_B((P_) ^ 1, (T_) + 1, 1); } \
    BAR(); SBAR0(); MFMA16(); VMEND_; BAR(); \
} while (0)

    // ---- prologue: stage tile 0 into buf0 (8 insts); wait first slot ----
    STAGE_A(0, 0, 0);
    STAGE_B(0, 0, 0);
    STAGE_A(0, 0, 1);
    STAGE_B(0, 0, 1);
    VM4();                   // slot0(0) landed; slot1(0) in flight
    BAR();

    // ---- main loop: tiles 0..62 stage t+1; tile 63 = tail (drain mid) ----
    #pragma unroll 1
    for (int t = 0; t < 62; t += 2) {
        TILE(0, t,     1, VM4(), VM4());
        TILE(1, t + 1, 1, VM4(), VM4());
    }
    TILE(0, 62, 1, VM4(), VM4());
    TILE(1, 63, 0, VM0(), (void)0);

    // ---- epilogue: C/D layout col = lane&15, row = q*4 + reg (validated) ----
    f16* Pz = part + (size_t)z * M_DIM * N_DIM;
    #pragma unroll
    for (int m = 0; m < 4; m++) {
        const int gm = row0 + wr * 64 + m * 16 + q * 4;
        #pragma unroll
        for (int n = 0; n < 4; n++) {
            const int gn = col0 + wc * 64 + n * 16 + rr;
            #pragma unroll
            for (int r2 = 0; r2 < 4; r2++)
                Pz[(size_t)(gm + r2) * N_DIM + gn] = (f16)acc[m][n][r2];
        }
    }
#undef STAGE_A
#undef STAGE_B
#undef READ_A
#undef READ_B
#undef MFMA16
#undef BAR
#undef SBAR0
#undef VM4
#undef VM0
#undef TILE
}

// ---------- kernel 3: reduce 2 fp16 partials + bias -> fp32 out ----------
__global__ __launch_bounds__(256) void reduce_kernel(
        const f16* __restrict__ part, const float* __restrict__ bias,
        float* __restrict__ out) {
    int p = blockIdx.x * 256 + threadIdx.x;
    const f16x4* P = (const f16x4*)part;
    f16x4 s0 = P[p];
    f16x4 s1 = P[p + MN4];
    float4 b  = ((const float4*)bias)[p & (N_DIM / 4 - 1)];
    float4 r;
    r.x = (float)s0[0] + (float)s1[0] + b.x;
    r.y = (float)s0[1] + (float)s1[1] + b.y;
    r.z = (float)s0[2] + (float)s1[2] + b.z;
    r.w = (float)s0[3] + (float)s1[3] + b.w;
    ((float4*)out)[p] = r;
}

// ---------- fallback (only if ws too small): naive fp32 tiled GEMM ----------
__global__ void gemm_fallback_kernel(const float* __restrict__ act,
                                     const float* __restrict__ W,
                                     const float* __restrict__ bias,
                                     float* __restrict__ out) {
    __shared__ float sA2[32][33];
    __shared__ float sB2[32][33];
    int tx = threadIdx.x, ty = threadIdx.y;
    int m = blockIdx.y * 32 + ty;
    int n = blockIdx.x * 32 + tx;
    float acc = 0.f;
    for (int kt = 0; kt < K_DIM; kt += 32) {
        int ka = kt + tx;
        int r = ka >> 10, kl = ka & (KL_ - 1);
        sA2[ty][tx] = act[((size_t)r * M_DIM + m) * KL_ + kl];
        sB2[ty][tx] = W[(size_t)(kt + ty) * N_DIM + n];
        __syncthreads();
        #pragma unroll
        for (int kk = 0; kk < 32; kk++) acc += sA2[ty][kk] * sB2[kk][tx];
        __syncthreads();
    }
    out[(size_t)m * N_DIM + n] = acc + bias[n];
}

extern "C" void kernel_launch(void* const* d_in, const int* in_sizes, int n_in,
                              void* d_out, int out_size, void* d_ws, size_t ws_size,
                              hipStream_t stream) {
    const float* all_act = (const float*)d_in[0];
    const float* local_W = (const float*)d_in[1];
    const float* bias    = (const float*)d_in[2];
    float* out = (float*)d_out;

    const size_t partBytes = (size_t)SPLITK * M_DIM * N_DIM * sizeof(f16);    // 16.8 MB
    const size_t elemsW    = (size_t)K_DIM * N_DIM;                           // 8.4M
    const size_t need = partBytes + elemsW * sizeof(f16);                     // ~33.6 MB

    if (ws_size < need) {
        gemm_fallback_kernel<<<dim3(N_DIM / 32, M_DIM / 32), dim3(32, 32), 0, stream>>>(
            all_act, local_W, bias, out);
        return;
    }

    f16* part  = (f16*)d_ws;
    f16* Bfrag = (f16*)((char*)d_ws + partBytes);

    conv_w_kernel<<<dim3(N_DIM / 64, K_DIM / 64), 256, 0, stream>>>(local_W, Bfrag);
    gemm_fused_kernel<<<256, 512, 0, stream>>>(all_act, Bfrag, part);
    reduce_kernel<<<MN4 / 256, 256, 0, stream>>>(part, bias, out);
}

// Round 7
// 294.431 us; speedup vs baseline: 1.2344x; 1.2344x over previous
//
#include <hip/hip_runtime.h>
#include <stdint.h>

// Problem constants (fixed by reference)
#define TP_      8
#define M_DIM    4096
#define K_DIM    8192
#define N_DIM    1024      // N_LOCAL
#define KL_      1024      // K_LOCAL
#define BM       256
#define BN       256
#define SPLITK   4
#define KSLICE   (K_DIM / SPLITK)   // 2048
#define MN4      (M_DIM * N_DIM / 4)
#define KCHUNKS  (K_DIM / 32)       // 256 k32-chunks per 16-row/col group
#define NBLK_A2  ((M_DIM / 16) * TP_)              // 256 mg x 8 r = 2048 A-blocks
#define NBLK_W2  (((N_DIM / 64) * (K_DIM / 64)) / 2)  // 1024 dual-tile W-blocks

typedef _Float16 f16;
typedef f16 f16x8 __attribute__((ext_vector_type(8)));
typedef f16 f16x4 __attribute__((ext_vector_type(4)));
typedef float f32x4 __attribute__((ext_vector_type(4)));

// 8x fp32 -> fp16 (v_cvt_f16_f32, RN)
__device__ __forceinline__ f16x8 cvt8(float4 a, float4 b) {
    f16x8 r;
    r[0] = (f16)a.x; r[1] = (f16)a.y; r[2] = (f16)a.z; r[3] = (f16)a.w;
    r[4] = (f16)b.x; r[5] = (f16)b.y; r[6] = (f16)b.z; r[7] = (f16)b.w;
    return r;
}

// async global->LDS, 16B/lane; dest = wave-uniform base + lane*16 (m104/m108)
__device__ __forceinline__ void lds_load16(const void* g, void* l) {
    __builtin_amdgcn_global_load_lds(
        (const __attribute__((address_space(1))) void*)g,
        (__attribute__((address_space(3))) void*)l, 16, 0, 0);
}

// Fragment-major layout (both operands): chunk c = group*KCHUNKS + k32;
// chunk holds 512 halfs; slot lane*8 = X[group*16 + (lane&15)][k32*32 + (lane>>4)*8 ..+8].
// A wave touching one chunk reads/writes base + lane*16B: ONE 1KB transaction.

// ---------- kernel 1: merged conversion, FULLY-SEQUENTIAL access test ----------
// r7 experiment: r4 (scatter) and r5 (2KB-window @4KB stride) both hit the
// same ~82us / ~2TB/s wall -> transaction shape within windows is not the
// limit. Last access-pattern hypothesis: DRAM locality of strided windows.
// A-block = one (mg, r) unit: reads 64KB MONOTONE-CONTIGUOUS from act,
// writes 32 consecutive chunks = 32KB MONOTONE-CONTIGUOUS to Afrag; the
// permutation lives in an LDS bounce ([16][1028] fp32, bank-balanced).
__global__ __launch_bounds__(512) void conv_aw_kernel(
        const float* __restrict__ act, const float* __restrict__ W,
        f16* __restrict__ Afrag, f16* __restrict__ Bfrag) {
    __shared__ __align__(16) char shraw[16 * 1028 * 4];   // 65792B (A) / 2x17408B (W)
    const int bid = blockIdx.x;
    const int t   = threadIdx.x;

    if (bid < NBLK_A2) {
        float (*ta)[1028] = (float(*)[1028])shraw;
        const int mg = bid >> 3;               // m-16-group 0..255
        const int r  = bid & 7;                // shard 0..7
        // phase 1: 64KB contiguous read -> LDS. inst i: block covers
        // bytes [i*8KB, (i+1)*8KB) of act[r][mg*16..+16][:], monotone.
        const float* base = act + ((size_t)r * M_DIM + mg * 16) * KL_;
        #pragma unroll
        for (int i = 0; i < 8; i++) {
            const int g = i * 2048 + t * 4;    // float idx in 16x1024 tile
            float4 v = *(const float4*)(base + g);
            *(float4*)&ta[g >> 10][g & 1023] = v;
        }
        __syncthreads();
        // phase 2: frag-pattern LDS read (8 lanes/bank-quad = balanced) +
        // 32KB contiguous frag-major write (chunks mg*256 + r*32 + c).
        const int l  = t & 63;
        const int wv = t >> 6;                 // wave 0..7
        const int rr = l & 15;
        const int q  = l >> 4;
        #pragma unroll
        for (int j = 0; j < 4; j++) {
            const int c = wv * 4 + j;          // chunk-in-tile (wave-uniform)
            float4 x = *(const float4*)&ta[rr][c * 32 + q * 8];
            float4 y = *(const float4*)&ta[rr][c * 32 + q * 8 + 4];
            size_t chunk = (size_t)mg * KCHUNKS + r * 32 + c;
            *(f16x8*)(Afrag + chunk * 512 + l * 8) = cvt8(x, y);  // 1KB/wave
        }
        return;
    }

    // W path: two 64x64 tiles per 512-thread block (r2-verified mapping, t->tt)
    const int sel = t >> 8;                    // 0..1
    const int tt  = t & 255;
    float (*tile)[68] = (float(*)[68])(shraw + sel * 17408);
    const int w2 = (bid - NBLK_A2) * 2 + sel;  // 0..2047
    const int n0 = (w2 & 15) * 64;
    const int k0 = (w2 >> 4) * 64;
    #pragma unroll
    for (int l = 0; l < 4; l++) {
        int kr = l * 16 + (tt >> 4);
        float4 v = *(const float4*)&W[(size_t)(k0 + kr) * N_DIM + n0 + (tt & 15) * 4];
        *(float4*)&tile[kr][(tt & 15) * 4] = v;
    }
    __syncthreads();
    const int jtl   = tt >> 6;
    const int kt32l = (tt >> 5) & 1;
    const int u     = tt & 31;
    const int rr    = u & 15;
    const int qp    = u >> 4;
    f16x8 h0, h1;
    #pragma unroll
    for (int kk = 0; kk < 8; kk++)
        h0[kk] = (f16)tile[kt32l * 32 + qp * 16 + kk][jtl * 16 + rr];
    #pragma unroll
    for (int kk = 0; kk < 8; kk++)
        h1[kk] = (f16)tile[kt32l * 32 + qp * 16 + 8 + kk][jtl * 16 + rr];
    size_t chunk = (size_t)(n0 / 16 + jtl) * KCHUNKS + (k0 / 32 + kt32l);
    f16* dst = Bfrag + chunk * 512;
    *(f16x8*)(dst + ((2 * qp)     * 16 + rr) * 8) = h0;
    *(f16x8*)(dst + ((2 * qp + 1) * 16 + rr) * 8) = h1;
}

// ---------- kernel 2: 8-phase-style deep-pipelined fragment GEMM (r2/r4-verified) ----------
// 256x256 tile, 8 waves (2M x 4N), BK=64 (2 k32), double-buffered 2x64KB LDS.
// Per K-tile: 4 phases x {ds_read subtile, stage 1 segment of tile t+1,
// barrier, setprio(1), 16 MFMA, setprio(0), [counted vmcnt], barrier}.
// vmcnt(4): consumed segment is always 2 segments (4 loads) older than the
// newest issue -> counted wait, never 0 in the main loop (T4).
// Partials stored fp16 (r4-verified: absmax floor unchanged).
__global__ __launch_bounds__(512, 2) void gemm_frag_kernel(
        const f16* __restrict__ Afrag,
        const f16* __restrict__ Bfrag,
        f16* __restrict__ part) {                 // (SPLITK, M, N) fp16
    __shared__ f16 sm[2][64 * 512];               // A chunks 0..31 (mg*2+k2), B 32..63

    const int tid  = threadIdx.x;
    const int w    = tid >> 6;                    // wave 0..7
    const int lane = tid & 63;
    const int q    = lane >> 4;
    const int rr   = lane & 15;
    const int wr   = w >> 2;                      // 0..1 (M)
    const int wc   = w & 3;                       // 0..3 (N)

    // XCD decode: xcd = (z<<1)|(mb&1). Per XCD: one z (B slice L2-resident),
    // 8 unique mb panels, all 4 nb (A panel reused x4 in L2).
    const int id   = blockIdx.x;                  // 0..255
    const int xcd  = id & 7;
    const int slot = id >> 3;                     // 0..31
    const int z    = xcd >> 1;                    // 0..3
    const int mb   = (slot >> 2) * 2 + (xcd & 1); // 0..15
    const int nb   = slot & 3;                    // 0..3
    const int row0 = mb * BM;
    const int col0 = nb * BN;
    const int kb32 = z * (KSLICE / 32);           // first k32 of this z-slice
    const int mg0  = row0 >> 4;
    const int ng0  = col0 >> 4;

    f32x4 acc[8][4];
    #pragma unroll
    for (int m = 0; m < 8; m++)
        #pragma unroll
        for (int n = 0; n < 4; n++)
            acc[m][n] = (f32x4){0.f, 0.f, 0.f, 0.f};

    f16x8 af[8];   // A fragments of current k2 half (reused across 2 n-phases)
    f16x8 bf[2];   // B fragments of current phase

#define STAGE_A(B_, T_, K2_) do { \
    const int kt32_ = kb32 + 2 * (T_) + (K2_); \
    _Pragma("unroll") \
    for (int j_ = 0; j_ < 2; j_++) { \
        const int mg_ = 2 * w + j_; \
        const f16* g_ = Afrag + ((size_t)(mg0 + mg_) * KCHUNKS + kt32_) * 512 + lane * 8; \
        lds_load16(g_, &sm[B_][(mg_ * 2 + (K2_)) * 512 + lane * 8]); \
    } \
} while (0)

#define STAGE_B(B_, T_, K2_) do { \
    const int kt32_ = kb32 + 2 * (T_) + (K2_); \
    _Pragma("unroll") \
    for (int j_ = 0; j_ < 2; j_++) { \
        const int ng_ = 2 * w + j_; \
        const f16* g_ = Bfrag + ((size_t)(ng0 + ng_) * KCHUNKS + kt32_) * 512 + lane * 8; \
        lds_load16(g_, &sm[B_][(32 + ng_ * 2 + (K2_)) * 512 + lane * 8]); \
    } \
} while (0)

#define READ_A(B_, K2_) do { \
    _Pragma("unroll") \
    for (int mi_ = 0; mi_ < 8; mi_++) \
        af[mi_] = *(const f16x8*)&sm[B_][((wr * 8 + mi_) * 2 + (K2_)) * 512 + lane * 8]; \
} while (0)

#define READ_B(B_, K2_, NH_) do { \
    _Pragma("unroll") \
    for (int ni_ = 0; ni_ < 2; ni_++) \
        bf[ni_] = *(const f16x8*)&sm[B_][(32 + (wc * 4 + (NH_) * 2 + ni_) * 2 + (K2_)) * 512 + lane * 8]; \
} while (0)

#define MFMA16(NH_) do { \
    __builtin_amdgcn_s_setprio(1); \
    _Pragma("unroll") \
    for (int mi_ = 0; mi_ < 8; mi_++) \
        _Pragma("unroll") \
        for (int ni_ = 0; ni_ < 2; ni_++) \
            acc[mi_][(NH_) * 2 + ni_] = __builtin_amdgcn_mfma_f32_16x16x32_f16( \
                af[mi_], bf[ni_], acc[mi_][(NH_) * 2 + ni_], 0, 0, 0); \
    __builtin_amdgcn_s_setprio(0); \
} while (0)

#define BAR() do { \
    asm volatile("" ::: "memory"); \
    __builtin_amdgcn_s_barrier(); \
    asm volatile("" ::: "memory"); \
} while (0)
#define SBAR0() __builtin_amdgcn_sched_barrier(0)
#define VM4() asm volatile("s_waitcnt vmcnt(4)" ::: "memory")
#define VM0() asm volatile("s_waitcnt vmcnt(0)" ::: "memory")

// One K-tile = 4 phases. VMMID_ guards A1/B1 of tile T_ before ph2 reads;
// VMEND_ guards A0/B0 of tile T_+1 before next tile's ph0 reads.
#define TILE(P_, T_, STG_, VMMID_, VMEND_) do { \
    READ_A(P_, 0); READ_B(P_, 0, 0); \
    if (STG_) STAGE_A((P_) ^ 1, (T_) + 1, 0); \
    BAR(); SBAR0(); MFMA16(0); BAR(); \
    READ_B(P_, 0, 1); \
    if (STG_) STAGE_B((P_) ^ 1, (T_) + 1, 0); \
    BAR(); SBAR0(); MFMA16(1); VMMID_; BAR(); \
    READ_A(P_, 1); READ_B(P_, 1, 0); \
    if (STG_) STAGE_A((P_) ^ 1, (T_) + 1, 1); \
    BAR(); SBAR0(); MFMA16(0); BAR(); \
    READ_B(P_, 1, 1); \
    if (STG_) STAGE_B((P_) ^ 1, (T_) + 1, 1); \
    BAR(); SBAR0(); MFMA16(1); VMEND_; BAR(); \
} while (0)

    // ---- prologue: stage tile 0 into buf0; wait for its first half ----
    STAGE_A(0, 0, 0);
    STAGE_B(0, 0, 0);
    STAGE_A(0, 0, 1);
    STAGE_B(0, 0, 1);
    VM4();                   // A0,B0(0) landed (A1,B1(0) still in flight)
    BAR();

    // ---- main loop: tiles 0..30 stage tile t+1; tail tile 31 drains ----
    #pragma unroll 1
    for (int t = 0; t < 30; t += 2) {
        TILE(0, t,     1, VM4(), VM4());
        TILE(1, t + 1, 1, VM4(), VM4());
    }
    TILE(0, 30, 1, VM4(), VM4());
    TILE(1, 31, 0, VM0(), (void)0);   // tail: no staging; drain once mid-tile

    // ---- epilogue: C/D layout col = lane&15, row = q*4 + reg (validated) ----
    f16* Pz = part + (size_t)z * M_DIM * N_DIM;
    #pragma unroll
    for (int m = 0; m < 8; m++) {
        const int gm = row0 + wr * 128 + m * 16 + q * 4;
        #pragma unroll
        for (int n = 0; n < 4; n++) {
            const int gn = col0 + wc * 64 + n * 16 + rr;
            #pragma unroll
            for (int r2 = 0; r2 < 4; r2++)
                Pz[(size_t)(gm + r2) * N_DIM + gn] = (f16)acc[m][n][r2];
        }
    }
#undef STAGE_A
#undef STAGE_B
#undef READ_A
#undef READ_B
#undef MFMA16
#undef BAR
#undef SBAR0
#undef VM4
#undef VM0
#undef TILE
}

// ---------- kernel 3: reduce 4 fp16 partials + bias -> fp32 out (r4-verified) ----------
__global__ __launch_bounds__(256) void reduce_kernel(
        const f16* __restrict__ part, const float* __restrict__ bias,
        float* __restrict__ out) {
    int p = blockIdx.x * 256 + threadIdx.x;
    const f16x4* P = (const f16x4*)part;
    f16x4 s0 = P[p];
    f16x4 s1 = P[p + MN4];
    f16x4 s2 = P[p + 2 * MN4];
    f16x4 s3 = P[p + 3 * MN4];
    float4 b  = ((const float4*)bias)[p & (N_DIM / 4 - 1)];
    float4 r;
    r.x = (float)s0[0] + (float)s1[0] + (float)s2[0] + (float)s3[0] + b.x;
    r.y = (float)s0[1] + (float)s1[1] + (float)s2[1] + (float)s3[1] + b.y;
    r.z = (float)s0[2] + (float)s1[2] + (float)s2[2] + (float)s3[2] + b.z;
    r.w = (float)s0[3] + (float)s1[3] + (float)s2[3] + (float)s3[3] + b.w;
    ((float4*)out)[p] = r;
}

// ---------- fallback (only if ws too small): naive fp32 tiled GEMM ----------
__global__ void gemm_fallback_kernel(const float* __restrict__ act,
                                     const float* __restrict__ W,
                                     const float* __restrict__ bias,
                                     float* __restrict__ out) {
    __shared__ float sA2[32][33];
    __shared__ float sB2[32][33];
    int tx = threadIdx.x, ty = threadIdx.y;
    int m = blockIdx.y * 32 + ty;
    int n = blockIdx.x * 32 + tx;
    float acc = 0.f;
    for (int kt = 0; kt < K_DIM; kt += 32) {
        int ka = kt + tx;
        int r = ka >> 10, kl = ka & (KL_ - 1);
        sA2[ty][tx] = act[((size_t)r * M_DIM + m) * KL_ + kl];
        sB2[ty][tx] = W[(size_t)(kt + ty) * N_DIM + n];
        __syncthreads();
        #pragma unroll
        for (int kk = 0; kk < 32; kk++) acc += sA2[ty][kk] * sB2[kk][tx];
        __syncthreads();
    }
    out[(size_t)m * N_DIM + n] = acc + bias[n];
}

extern "C" void kernel_launch(void* const* d_in, const int* in_sizes, int n_in,
                              void* d_out, int out_size, void* d_ws, size_t ws_size,
                              hipStream_t stream) {
    const float* all_act = (const float*)d_in[0];
    const float* local_W = (const float*)d_in[1];
    const float* bias    = (const float*)d_in[2];
    float* out = (float*)d_out;

    const size_t partBytes = (size_t)SPLITK * M_DIM * N_DIM * sizeof(f16);    // 33.6 MB
    const size_t elemsA    = (size_t)M_DIM * K_DIM;                           // 33.5M
    const size_t elemsW    = (size_t)K_DIM * N_DIM;                           // 8.4M
    const size_t need = partBytes + elemsA * sizeof(f16) + elemsW * sizeof(f16);  // ~117 MB

    if (ws_size < need) {
        gemm_fallback_kernel<<<dim3(N_DIM / 32, M_DIM / 32), dim3(32, 32), 0, stream>>>(
            all_act, local_W, bias, out);
        return;
    }

    f16* part  = (f16*)d_ws;
    f16* Afrag = (f16*)((char*)d_ws + partBytes);
    f16* Bfrag = Afrag + elemsA;

    conv_aw_kernel<<<NBLK_A2 + NBLK_W2, 512, 0, stream>>>(all_act, local_W, Afrag, Bfrag);
    gemm_frag_kernel<<<256, 512, 0, stream>>>(Afrag, Bfrag, part);
    reduce_kernel<<<MN4 / 256, 256, 0, stream>>>(part, bias, out);
}